// Round 8
// baseline (1984.619 us; speedup 1.0000x reference)
//
#include <hip/hip_runtime.h>
#include <math.h>

#define NU 20000
#define NI 20000
#define L  50
#define NODES 32   // per block

typedef __attribute__((ext_vector_type(8))) short bfx8;
typedef __attribute__((ext_vector_type(4))) float f32x4;
typedef unsigned short u16;
typedef unsigned char  u8;
typedef unsigned int   u32;

// ---- dynamic LDS layout (bytes), total 78464 (2 blocks/CU) ----
#define OFF_WI    0        // 49152: serial Wi blocked [2][2][192][32]bf16
                           //   PH0 scratch: sTM i32[1600] + sNID i32[1600]
                           //   PH2 scratch: sGLT u16[128][72] + sTED f32[32][68]
                           //   PH6 scratch: sHS u16[32][136] + sA9 u16[32][136] + sTKT u16[64][72]
#define OFF_H     49152    // 9216: per-wave h  u16[4][16][72]  (PH2 scratch: sDST u16[32][72])
#define OFF_RID   58368    // 3328: u16[32][52] sorted row ids
#define OFF_EF    61696    // 6656: f32[32][52] ted+fwd scores -> alpha
#define OFF_EB    68352    // 6656: f32[32][52] bwd scores  (PH6: sBETA u16[32][72])
#define OFF_ORD   75008    // 1664: u8[32][52]
#define OFF_ARE   76672    // 1664: u8[32][52]
#define OFF_LASTN 78336    // 128:  i32[32]
#define SMEM_SZ   78464

// ---------------------------------------------------------------------------
__device__ __forceinline__ float bflo(u32 u) { return __uint_as_float(u << 16); }
__device__ __forceinline__ float bfhi(u32 u) { return __uint_as_float(u & 0xffff0000u); }
__device__ __forceinline__ u16 f2bf(float f) {
    u32 u = __float_as_uint(f);
    u = u + 0x7fffu + ((u >> 16) & 1u);      // RNE
    return (u16)(u >> 16);
}
__device__ __forceinline__ float bf2f(u16 s) {
    return __uint_as_float(((u32)s) << 16);
}
__device__ __forceinline__ float fsig(float x) {
    return __builtin_amdgcn_rcpf(1.f + __expf(-x));
}
__device__ __forceinline__ float ftanh(float x) {
    float t = fminf(2.f * x, 80.f);
    float e2 = __expf(t);
    return (e2 - 1.f) * __builtin_amdgcn_rcpf(e2 + 1.f);
}
__device__ __forceinline__ bfx8 pack_bf8(const float* p) {
    float4 a = ((const float4*)p)[0];
    float4 b = ((const float4*)p)[1];
    bfx8 r;
    r[0]=(short)f2bf(a.x); r[1]=(short)f2bf(a.y); r[2]=(short)f2bf(a.z); r[3]=(short)f2bf(a.w);
    r[4]=(short)f2bf(b.x); r[5]=(short)f2bf(b.y); r[6]=(short)f2bf(b.z); r[7]=(short)f2bf(b.w);
    return r;
}
__device__ __forceinline__ bfx8 pack2(float4 a, float4 b) {
    bfx8 r;
    r[0]=(short)f2bf(a.x); r[1]=(short)f2bf(a.y); r[2]=(short)f2bf(a.z); r[3]=(short)f2bf(a.w);
    r[4]=(short)f2bf(b.x); r[5]=(short)f2bf(b.y); r[6]=(short)f2bf(b.z); r[7]=(short)f2bf(b.w);
    return r;
}
__device__ __forceinline__ float xget(uint2 u, int r) {
    switch (r) {
        case 0: return bflo(u.x);
        case 1: return bfhi(u.x);
        case 2: return bflo(u.y);
        default: return bfhi(u.y);
    }
}

// ---------------------------------------------------------------------------
// K1: Y[r][d] = sum_k X[r][k] * W[d][k]
// ---------------------------------------------------------------------------
__global__ __launch_bounds__(256) void hid_kernel(const float* __restrict__ X,
                                                  const float* __restrict__ W,
                                                  float* __restrict__ Y, int N)
{
    __shared__ float sW[64][65];
    int tid = threadIdx.x;
    for (int i = tid; i < 64 * 64; i += 256) sW[i >> 6][i & 63] = W[i];
    __syncthreads();
    int r = blockIdx.x * 4 + (tid >> 6);
    int d = tid & 63;
    if (r >= N) return;
    const float* x = X + (size_t)r * 64;
    float acc = 0.f;
    #pragma unroll
    for (int k = 0; k < 64; ++k) acc += x[k] * sW[d][k];
    Y[(size_t)r * 64 + d] = acc;
}

// ---------------------------------------------------------------------------
// K3: out[r][d] = tanh( U[d][:64].A[r] + U[d][64:].F[r] )
// ---------------------------------------------------------------------------
__global__ __launch_bounds__(256) void upd_kernel(const float* __restrict__ A,
                                                  const float* __restrict__ F,
                                                  const float* __restrict__ U,
                                                  float* __restrict__ out, int N)
{
    __shared__ float sU[64][130];
    int tid = threadIdx.x;
    for (int i = tid; i < 64 * 128; i += 256) sU[i >> 7][i & 127] = U[i];
    __syncthreads();
    int r = blockIdx.x * 4 + (tid >> 6);
    int d = tid & 63;
    if (r >= N) return;
    const float* a = A + (size_t)r * 64;
    const float* f = F + (size_t)r * 64;
    float acc = 0.f;
    #pragma unroll
    for (int k = 0; k < 64; ++k) acc += a[k] * sU[d][k];
    #pragma unroll
    for (int k = 0; k < 64; ++k) acc += f[k] * sU[d][64 + k];
    out[(size_t)r * 64 + d] = tanhf(acc);
}

// ---------------------------------------------------------------------------
// K2: 32 nodes per 256-thread block; wave wv owns dir = wv>>1 for node half
// (wv&1)*16. Each wave runs produce(xw via MFMA, Wi from LDS) + consume
// (gh via MFMA, Wh in regs) + gates itself: NO barriers in the 50-step loop.
// Two passes: 0) attention scores via v = glin^T.dst ; 1) hsum = sum alpha*h.
// Register budget note: __launch_bounds__(256,1) — the ",2" variant makes the
// allocator cap at 128 VGPR and spill (rounds 5/6: WRITE_SIZE 51-77 MB).
// ---------------------------------------------------------------------------
__global__ __launch_bounds__(256, 1) void reduce32(
    const float* __restrict__ src_hid,   // [Nsrc][64]
    const float* __restrict__ dst_hid,   // [N][64]
    const int*   __restrict__ nbr_idx,   // [N][L]
    const int*   __restrict__ nbr_time,  // [N][L]
    const float* __restrict__ te,        // [L][64]
    const float* __restrict__ te_k,      // [L][64]
    const float* __restrict__ Wi,        // [2][192][64]
    const float* __restrict__ Wh,        // [2][192][64]
    const float* __restrict__ bi,        // [2][192]
    const float* __restrict__ bh,        // [2][192]
    const float* __restrict__ glin,      // [64][128]
    const float* __restrict__ agg,       // [64][128]
    float* __restrict__ out)             // [N][64]
{
    extern __shared__ __align__(16) char smem[];
    u16*   sWI    = (u16*)(smem + OFF_WI);
    u16*   sRIDp  = (u16*)(smem + OFF_RID);
    float* sEF    = (float*)(smem + OFF_EF);
    float* sEB    = (float*)(smem + OFF_EB);
    u8*    sORD   = (u8*)(smem + OFF_ORD);
    u8*    sARE   = (u8*)(smem + OFF_ARE);
    int*   sLASTN = (int*)(smem + OFF_LASTN);

    const int tid  = threadIdx.x;
    const int lane = tid & 63;
    const int wv   = tid >> 6;            // 0..3
    const int l15  = lane & 15;
    const int grp  = lane >> 4;           // 0..3
    const int lk8  = grp * 8;
    const int nb   = blockIdx.x * NODES;
    const int dir    = wv >> 1;           // 0=fwd 1=bwd
    const int base16 = (wv & 1) * 16;     // node half owned by this wave

    u16* sHw = (u16*)(smem + OFF_H) + wv * 16 * 72;   // per-wave h [16][72]

    // ---- PH0: times/ids -> stable rank, argmax(first), sorted row ids ----
    int* sTM  = (int*)(smem + OFF_WI);
    int* sNID = sTM + NODES * L;
    for (int p = tid; p < NODES * L; p += 256) {
        sTM[p]  = nbr_time[(size_t)nb * L + p];
        sNID[p] = nbr_idx[(size_t)nb * L + p];
    }
    __syncthreads();
    for (int p = tid; p < NODES * L; p += 256) {
        int m = p / L, l = p - m * L;
        int tl = sTM[p], rank = 0;
        for (int mm = 0; mm < L; ++mm) {
            int tm = sTM[m * L + mm];
            rank += (tm < tl) || (tm == tl && mm < l);
        }
        sORD[m * 52 + rank] = (u8)l;
        sARE[m * 52 + l]    = (u8)(L - 1 - rank);
    }
    if (tid < NODES) {
        int best = 0, bt = sTM[tid * L];
        for (int mm = 1; mm < L; ++mm) {
            int tm = sTM[tid * L + mm];
            if (tm > bt) { bt = tm; best = mm; }
        }
        sLASTN[tid] = sNID[tid * L + best];
    }
    __syncthreads();
    // sRID (u16) + dst staging (region H)
    u16* sDST = (u16*)(smem + OFF_H);
    for (int p = tid; p < NODES * L; p += 256) {
        int m = p / L, t = p - m * L;
        sRIDp[m * 52 + t] = (u16)sNID[m * L + sORD[m * 52 + t]];
    }
    for (int p = tid; p < NODES * 64; p += 256) {
        int m = p >> 6, d = p & 63;
        sDST[m * 72 + d] = f2bf(dst_hid[(size_t)(nb + m) * 64 + d]);
    }
    __syncthreads();

    // ---- PH2a: stage glin^T ----
    u16* sGLT = (u16*)(smem + OFF_WI);             // [128][72]
    float* sTED = (float*)(smem + OFF_WI + 18432); // [32][68]
    for (int p = tid; p < 8192; p += 256) {
        int d = p >> 7, j = p & 127;
        sGLT[j * 72 + d] = f2bf(glin[(size_t)d * 128 + j]);
    }
    __syncthreads();

    // ---- PH2b: v-GEMM (vv stays in regs) + tedst GEMM ----
    float vv[4][4];
    {
        const u16* drow = sDST + (base16 + l15) * 72;
        bfx8 a0 = *(const bfx8*)(drow + lk8);
        bfx8 a1 = *(const bfx8*)(drow + 32 + lk8);
        #pragma unroll
        for (int nt = 0; nt < 4; ++nt) {
            const u16* gr = sGLT + (dir * 64 + nt * 16 + l15) * 72;
            bfx8 b0 = *(const bfx8*)(gr + lk8);
            bfx8 b1 = *(const bfx8*)(gr + 32 + lk8);
            f32x4 acc = {0.f, 0.f, 0.f, 0.f};
            acc = __builtin_amdgcn_mfma_f32_16x16x32_bf16(a0, b0, acc, 0, 0, 0);
            acc = __builtin_amdgcn_mfma_f32_16x16x32_bf16(a1, b1, acc, 0, 0, 0);
            #pragma unroll
            for (int r = 0; r < 4; ++r) vv[nt][r] = acc[r];
        }
    }
    #pragma unroll
    for (int e = 0; e < 2; ++e) {
        int it = wv * 2 + e, mt = it >> 2, nt = it & 3;
        const u16* drow = sDST + (mt * 16 + l15) * 72;
        bfx8 a0 = *(const bfx8*)(drow + lk8);
        bfx8 a1 = *(const bfx8*)(drow + 32 + lk8);
        int j = nt * 16 + l15;
        const float* tr = te + (size_t)(j < L ? j : 0) * 64;
        bfx8 b0 = pack_bf8(tr + lk8);
        bfx8 b1 = pack_bf8(tr + 32 + lk8);
        f32x4 acc = {0.f, 0.f, 0.f, 0.f};
        acc = __builtin_amdgcn_mfma_f32_16x16x32_bf16(a0, b0, acc, 0, 0, 0);
        acc = __builtin_amdgcn_mfma_f32_16x16x32_bf16(a1, b1, acc, 0, 0, 0);
        #pragma unroll
        for (int r = 0; r < 4; ++r)
            sTED[(mt * 16 + grp * 4 + r) * 68 + j] = acc[r];
    }
    __syncthreads();

    // ---- PH2c: sEF init = ted gather ----
    for (int p = tid; p < NODES * L; p += 256) {
        int m = p / L, l = p - m * L;
        sEF[m * 52 + l] = sTED[m * 68 + sARE[m * 52 + l]];
    }
    __syncthreads();

    // ---- PH2d: stage Wi blocked [dir][kt][192][32] ----
    for (int p = tid; p < 2 * 192 * 64; p += 256) {
        int kk  = p & 63;
        int row = (p >> 6) % 192;
        int dr  = p / (192 * 64);
        sWI[(((dr * 2 + (kk >> 5)) * 192 + row) << 5) + (kk & 31)]
            = f2bf(Wi[(size_t)(dr * 192 + row) * 64 + kk]);
    }
    // Wh fragments + packed biases (bi lo / bh hi, bf16) in regs
    bfx8 whf[12][2];
    u32 bib[12];
    #pragma unroll
    for (int nt = 0; nt < 12; ++nt) {
        const float* wrow = Wh + (size_t)(dir * 192 + nt * 16 + l15) * 64;
        whf[nt][0] = pack_bf8(wrow + lk8);
        whf[nt][1] = pack_bf8(wrow + 32 + lk8);
        bib[nt] = (u32)f2bf(bi[dir * 192 + nt * 16 + l15])
                | ((u32)f2bf(bh[dir * 192 + nt * 16 + l15]) << 16);
    }
    __syncthreads();

    float S[4][4];
    uint2 xcur[12];
    float hp[4][4];

    auto produce = [&](float4 m0, float4 m1, float4 m2, float4 m3) {
        bfx8 a0 = pack2(m0, m1);
        bfx8 a1 = pack2(m2, m3);
        #pragma unroll
        for (int nt = 0; nt < 12; ++nt) {
            bfx8 b0 = *(const bfx8*)(sWI + (((dir * 2 + 0) * 192 + nt * 16 + l15) << 5) + lk8);
            bfx8 b1 = *(const bfx8*)(sWI + (((dir * 2 + 1) * 192 + nt * 16 + l15) << 5) + lk8);
            f32x4 acc = {0.f, 0.f, 0.f, 0.f};
            acc = __builtin_amdgcn_mfma_f32_16x16x32_bf16(a0, b0, acc, 0, 0, 0);
            acc = __builtin_amdgcn_mfma_f32_16x16x32_bf16(a1, b1, acc, 0, 0, 0);
            float bia = bflo(bib[nt]);
            uint2 pk;
            pk.x = (u32)f2bf(acc[0] + bia) | ((u32)f2bf(acc[1] + bia) << 16);
            pk.y = (u32)f2bf(acc[2] + bia) | ((u32)f2bf(acc[3] + bia) << 16);
            xcur[nt] = pk;
        }
    };

    auto run_pass = [&](int pass) {
        // zero h
        #pragma unroll
        for (int c = 0; c < 4; ++c)
            #pragma unroll
            for (int r = 0; r < 4; ++r) {
                hp[c][r] = 0.f;
                if (pass == 1) S[c][r] = 0.f;
                sHw[(grp * 4 + r) * 72 + c * 16 + l15] = 0;
            }
        // prologue: xw for s=0
        {
            int tt = dir ? (L - 1) : 0;
            const float4* mr = (const float4*)(src_hid + (size_t)sRIDp[(base16 + l15) * 52 + tt] * 64);
            float4 m0 = mr[grp * 2], m1 = mr[grp * 2 + 1];
            float4 m2 = mr[8 + grp * 2], m3 = mr[9 + grp * 2];
            produce(m0, m1, m2, m3);
        }
        for (int s = 0; s < L; ++s) {
            // issue next-step mail loads early (hidden under gates)
            float4 n0, n1, n2, n3;
            if (s + 1 < L) {
                int tt = dir ? (L - 2 - s) : (s + 1);
                const float4* mr = (const float4*)(src_hid + (size_t)sRIDp[(base16 + l15) * 52 + tt] * 64);
                n0 = mr[grp * 2]; n1 = mr[grp * 2 + 1];
                n2 = mr[8 + grp * 2]; n3 = mr[9 + grp * 2];
            }
            // consume step s: h fragments from previous step
            bfx8 a0 = *(const bfx8*)(sHw + l15 * 72 + lk8);
            bfx8 a1 = *(const bfx8*)(sHw + l15 * 72 + 32 + lk8);
            int t = dir ? (L - 1 - s) : s;
            float al[4];
            if (pass == 1) {
                #pragma unroll
                for (int r = 0; r < 4; ++r)
                    al[r] = sEF[(base16 + grp * 4 + r) * 52 + t];   // alpha (aliased)
            }
            float pe[4] = {0.f, 0.f, 0.f, 0.f};
            // column-split: 6 MFMAs for gate-column c, then gate column c
            #pragma unroll
            for (int c = 0; c < 4; ++c) {
                f32x4 zr = {0.f, 0.f, 0.f, 0.f};
                f32x4 zz4 = {0.f, 0.f, 0.f, 0.f};
                f32x4 zn4 = {0.f, 0.f, 0.f, 0.f};
                zr  = __builtin_amdgcn_mfma_f32_16x16x32_bf16(a0, whf[c][0],     zr,  0, 0, 0);
                zr  = __builtin_amdgcn_mfma_f32_16x16x32_bf16(a1, whf[c][1],     zr,  0, 0, 0);
                zz4 = __builtin_amdgcn_mfma_f32_16x16x32_bf16(a0, whf[4 + c][0], zz4, 0, 0, 0);
                zz4 = __builtin_amdgcn_mfma_f32_16x16x32_bf16(a1, whf[4 + c][1], zz4, 0, 0, 0);
                zn4 = __builtin_amdgcn_mfma_f32_16x16x32_bf16(a0, whf[8 + c][0], zn4, 0, 0, 0);
                zn4 = __builtin_amdgcn_mfma_f32_16x16x32_bf16(a1, whf[8 + c][1], zn4, 0, 0, 0);
                float bhr = bfhi(bib[c]);
                float bhz = bfhi(bib[4 + c]);
                float bhn = bfhi(bib[8 + c]);
                #pragma unroll
                for (int r = 0; r < 4; ++r) {
                    float ghr = zr[r]  + bhr;
                    float ghz = zz4[r] + bhz;
                    float ghn = zn4[r] + bhn;
                    float xwr = xget(xcur[c], r);
                    float xwz = xget(xcur[4 + c], r);
                    float xwn = xget(xcur[8 + c], r);
                    float rr = fsig(xwr + ghr);
                    float zz = fsig(xwz + ghz);
                    float nn = ftanh(xwn + rr * ghn);
                    float h  = (1.f - zz) * nn + zz * hp[c][r];
                    hp[c][r] = h;
                    sHw[(grp * 4 + r) * 72 + c * 16 + l15] = f2bf(h);
                    if (pass == 0) pe[r] += h * vv[c][r];
                    else           S[c][r] += al[r] * h;
                }
            }
            if (pass == 0) {
                #pragma unroll
                for (int r = 0; r < 4; ++r) {
                    #pragma unroll
                    for (int msk = 1; msk < 16; msk <<= 1)
                        pe[r] += __shfl_xor(pe[r], msk, 64);
                }
                if (l15 == 0) {
                    #pragma unroll
                    for (int r = 0; r < 4; ++r) {
                        int idx = (base16 + grp * 4 + r) * 52 + t;
                        if (dir == 0) sEF[idx] += pe[r];
                        else          sEB[idx]  = pe[r];
                    }
                }
            }
            if (s + 1 < L) produce(n0, n1, n2, n3);   // xw for s+1
        }
    };

    // ---- PH3: pass 0 (scores) ----
    run_pass(0);
    __syncthreads();

    // ---- PH4: softmax; alpha overwrites sEF ----
    if (tid < NODES) {
        int m = tid;
        float mx = -1e30f;
        for (int t = 0; t < L; ++t) {
            float v = (sEF[m * 52 + t] + sEB[m * 52 + t]) * 0.125f;
            sEF[m * 52 + t] = v;
            mx = fmaxf(mx, v);
        }
        float sum = 0.f;
        for (int t = 0; t < L; ++t) {
            float ex = __expf(sEF[m * 52 + t] - mx);
            sEF[m * 52 + t] = ex;
            sum += ex;
        }
        float rs = __builtin_amdgcn_rcpf(sum);
        for (int t = 0; t < L; ++t) sEF[m * 52 + t] *= rs;
    }
    __syncthreads();

    // ---- PH5: pass 1 (weighted hidden sum) ----
    run_pass(1);
    __syncthreads();

    // ---- PH6: epilogue ----
    u16* sHS   = (u16*)(smem + OFF_WI);          // [32][136] bf16 hsum f||b
    u16* sA9   = sHS + 32 * 136;                 // [32][136] bf16 hid || last_em
    u16* sTKT  = sA9 + 32 * 136;                 // [64][72]  bf16 te_k^T padded
    u16* sBETA = (u16*)(smem + OFF_EB);          // [32][72]  bf16

    #pragma unroll
    for (int c = 0; c < 4; ++c)
        #pragma unroll
        for (int r = 0; r < 4; ++r)
            sHS[(base16 + grp * 4 + r) * 136 + dir * 64 + c * 16 + l15] = f2bf(S[c][r]);
    if (tid < NODES) {
        for (int t = 0; t < L; ++t)
            sBETA[tid * 72 + sARE[tid * 52 + t]] = f2bf(sEF[tid * 52 + t]);
        for (int j = L; j < 64; ++j) sBETA[tid * 72 + j] = 0;
    }
    for (int p = tid; p < 4096; p += 256) {
        int j = p >> 6, d = p & 63;
        sTKT[d * 72 + j] = (j < L) ? f2bf(te_k[(size_t)j * 64 + d]) : (u16)0;
    }
    for (int p = tid; p < NODES * 64; p += 256) {
        int m = p >> 6, d = p & 63;
        sA9[m * 136 + 64 + d] = f2bf(src_hid[(size_t)sLASTN[m] * 64 + d]);
    }
    __syncthreads();

    // hid[m][d] = glin[d][:].hsum[m] + te_k^T[d][:].beta[m]
    #pragma unroll
    for (int e = 0; e < 2; ++e) {
        int it = wv * 2 + e, mt = it >> 2, nt = it & 3;
        bfx8 aH[4], aB[2];
        #pragma unroll
        for (int kt = 0; kt < 4; ++kt)
            aH[kt] = *(const bfx8*)(sHS + (mt * 16 + l15) * 136 + kt * 32 + lk8);
        #pragma unroll
        for (int kt = 0; kt < 2; ++kt)
            aB[kt] = *(const bfx8*)(sBETA + (mt * 16 + l15) * 72 + kt * 32 + lk8);
        f32x4 acc = {0.f, 0.f, 0.f, 0.f};
        #pragma unroll
        for (int kt = 0; kt < 4; ++kt) {
            bfx8 b = pack_bf8(glin + (size_t)(nt * 16 + l15) * 128 + kt * 32 + lk8);
            acc = __builtin_amdgcn_mfma_f32_16x16x32_bf16(aH[kt], b, acc, 0, 0, 0);
        }
        #pragma unroll
        for (int kt = 0; kt < 2; ++kt) {
            bfx8 b = *(const bfx8*)(sTKT + (nt * 16 + l15) * 72 + kt * 32 + lk8);
            acc = __builtin_amdgcn_mfma_f32_16x16x32_bf16(aB[kt], b, acc, 0, 0, 0);
        }
        #pragma unroll
        for (int r = 0; r < 4; ++r)
            sA9[(mt * 16 + grp * 4 + r) * 136 + nt * 16 + l15] = f2bf(acc[r]);
    }
    __syncthreads();

    // out[m][d] = agg[d][:64].hid[m] + agg[d][64:].last_em[m]
    #pragma unroll
    for (int e = 0; e < 2; ++e) {
        int it = wv * 2 + e, mt = it >> 2, nt = it & 3;
        bfx8 aA[4];
        #pragma unroll
        for (int kt = 0; kt < 4; ++kt)
            aA[kt] = *(const bfx8*)(sA9 + (mt * 16 + l15) * 136 + kt * 32 + lk8);
        f32x4 acc = {0.f, 0.f, 0.f, 0.f};
        #pragma unroll
        for (int kt = 0; kt < 4; ++kt) {
            bfx8 b = pack_bf8(agg + (size_t)(nt * 16 + l15) * 128 + kt * 32 + lk8);
            acc = __builtin_amdgcn_mfma_f32_16x16x32_bf16(aA[kt], b, acc, 0, 0, 0);
        }
        #pragma unroll
        for (int r = 0; r < 4; ++r)
            out[(size_t)(nb + mt * 16 + grp * 4 + r) * 64 + nt * 16 + l15] = acc[r];
    }
}

// ---------------------------------------------------------------------------
extern "C" void kernel_launch(void* const* d_in, const int* in_sizes, int n_in,
                              void* d_out, int out_size, void* d_ws, size_t ws_size,
                              hipStream_t stream)
{
    const float* user_feat     = (const float*)d_in[0];
    const float* item_feat     = (const float*)d_in[1];
    const int*   item_nbr_idx  = (const int*)d_in[2];
    const int*   item_nbr_time = (const int*)d_in[3];
    const int*   user_nbr_idx  = (const int*)d_in[4];
    const int*   user_nbr_time = (const int*)d_in[5];
    const float* W_user        = (const float*)d_in[6];
    const float* W_item        = (const float*)d_in[7];
    const float* u_te          = (const float*)d_in[8];
    const float* u_te_k        = (const float*)d_in[9];
    const float* i_te          = (const float*)d_in[10];
    const float* i_te_k        = (const float*)d_in[11];
    const float* gru_u_Wi      = (const float*)d_in[12];
    const float* gru_u_Wh      = (const float*)d_in[13];
    const float* gru_u_bi      = (const float*)d_in[14];
    const float* gru_u_bh      = (const float*)d_in[15];
    const float* gru_i_Wi      = (const float*)d_in[16];
    const float* gru_i_Wh      = (const float*)d_in[17];
    const float* gru_i_bi      = (const float*)d_in[18];
    const float* gru_i_bh      = (const float*)d_in[19];
    const float* gru_lin_u     = (const float*)d_in[20];
    const float* gru_lin_i     = (const float*)d_in[21];
    const float* agg_u         = (const float*)d_in[22];
    const float* agg_i         = (const float*)d_in[23];
    const float* upd_u         = (const float*)d_in[24];
    const float* upd_i         = (const float*)d_in[25];

    float* ws       = (float*)d_ws;
    float* user_hid = ws;
    float* item_hid = user_hid + NU * 64;
    float* item_agg = item_hid + NI * 64;
    float* user_agg = item_agg + NI * 64;

    (void)hipFuncSetAttribute((const void*)reduce32,
                              hipFuncAttributeMaxDynamicSharedMemorySize, SMEM_SZ);

    hid_kernel<<<NU / 4, 256, 0, stream>>>(user_feat, W_user, user_hid, NU);
    hid_kernel<<<NI / 4, 256, 0, stream>>>(item_feat, W_item, item_hid, NI);

    // 'by': user -> item, per item node
    reduce32<<<NI / NODES, 256, SMEM_SZ, stream>>>(user_hid, item_hid,
        item_nbr_idx, item_nbr_time, i_te, i_te_k,
        gru_i_Wi, gru_i_Wh, gru_i_bi, gru_i_bh, gru_lin_i, agg_i, item_agg);

    // 'pby': item -> user, per user node
    reduce32<<<NU / NODES, 256, SMEM_SZ, stream>>>(item_hid, user_hid,
        user_nbr_idx, user_nbr_time, u_te, u_te_k,
        gru_u_Wi, gru_u_Wh, gru_u_bi, gru_u_bh, gru_lin_u, agg_u, user_agg);

    float* out = (float*)d_out;
    upd_kernel<<<NU / 4, 256, 0, stream>>>(user_agg, user_feat, upd_u, out, NU);
    upd_kernel<<<NI / 4, 256, 0, stream>>>(item_agg, item_feat, upd_i, out + NU * 64, NI);
}

// Round 9
// 1410.526 us; speedup vs baseline: 1.4070x; 1.4070x over previous
//
#include <hip/hip_runtime.h>
#include <math.h>

#define NU 20000
#define NI 20000
#define L  50
#define NODES 32   // per block

typedef __attribute__((ext_vector_type(8))) short bfx8;
typedef __attribute__((ext_vector_type(4))) float f32x4;
typedef unsigned short u16;
typedef unsigned char  u8;
typedef unsigned int   u32;

// ---- dynamic LDS layout (bytes), total 78464 (2 blocks/CU, LDS-capped) ----
#define OFF_WI    0        // 49152: Wi blocked+swizzled [2][2][192][32]bf16
#define OFF_H     49152    // 9216: per-wave h  u16[4][16][72]
#define OFF_RID   58368    // 3328: u16[32][52] sorted row ids
#define OFF_EF    61696    // 6656: f32[32][52] ted+fwd scores -> alpha
#define OFF_EB    68352    // 6656: f32[32][52] bwd scores  (PH6: sBETA)
#define OFF_ORD   75008    // 1664: u8[32][52]
#define OFF_ARE   76672    // 1664: u8[32][52]
#define OFF_LASTN 78336    // 128:  i32[32]
#define SMEM_SZ   78464

// ---------------------------------------------------------------------------
__device__ __forceinline__ u16 f2bf(float f) {
    u32 u = __float_as_uint(f);
    u = u + 0x7fffu + ((u >> 16) & 1u);      // RNE
    return (u16)(u >> 16);
}
__device__ __forceinline__ float bf2f(u16 s) {
    return __uint_as_float(((u32)s) << 16);
}
__device__ __forceinline__ u32 cvtpk(float lo, float hi) {
    u32 d;
    asm("v_cvt_pk_bf16_f32 %0, %1, %2" : "=v"(d) : "v"(lo), "v"(hi));
    return d;
}
__device__ __forceinline__ float fsig(float x) {
    return __builtin_amdgcn_rcpf(1.f + __expf(-x));
}
__device__ __forceinline__ float ftanh(float x) {
    float t = __expf(x + x);
    float u = __builtin_amdgcn_rcpf(t + 1.f);
    return __builtin_fmaf(-2.f, u, 1.f);     // +-inf safe: -> +-1
}
__device__ __forceinline__ bfx8 pack_bf8(const float* p) {
    float4 a = ((const float4*)p)[0];
    float4 b = ((const float4*)p)[1];
    bfx8 r;
    r[0]=(short)f2bf(a.x); r[1]=(short)f2bf(a.y); r[2]=(short)f2bf(a.z); r[3]=(short)f2bf(a.w);
    r[4]=(short)f2bf(b.x); r[5]=(short)f2bf(b.y); r[6]=(short)f2bf(b.z); r[7]=(short)f2bf(b.w);
    return r;
}

// ---------------------------------------------------------------------------
// K1: Y = X @ W.T   (also writes bf16 copy Yb for the reduce kernel)
// ---------------------------------------------------------------------------
__global__ __launch_bounds__(256) void hid_kernel(const float* __restrict__ X,
                                                  const float* __restrict__ W,
                                                  float* __restrict__ Y,
                                                  u16* __restrict__ Yb, int N)
{
    __shared__ float sW[64][65];
    int tid = threadIdx.x;
    for (int i = tid; i < 64 * 64; i += 256) sW[i >> 6][i & 63] = W[i];
    __syncthreads();
    int r = blockIdx.x * 4 + (tid >> 6);
    int d = tid & 63;
    if (r >= N) return;
    const float* x = X + (size_t)r * 64;
    float acc = 0.f;
    #pragma unroll
    for (int k = 0; k < 64; ++k) acc += x[k] * sW[d][k];
    Y[(size_t)r * 64 + d]  = acc;
    Yb[(size_t)r * 64 + d] = f2bf(acc);
}

// ---------------------------------------------------------------------------
// K3: out[r][d] = tanh( U[d][:64].A[r] + U[d][64:].F[r] )
// ---------------------------------------------------------------------------
__global__ __launch_bounds__(256) void upd_kernel(const float* __restrict__ A,
                                                  const float* __restrict__ F,
                                                  const float* __restrict__ U,
                                                  float* __restrict__ out, int N)
{
    __shared__ float sU[64][130];
    int tid = threadIdx.x;
    for (int i = tid; i < 64 * 128; i += 256) sU[i >> 7][i & 127] = U[i];
    __syncthreads();
    int r = blockIdx.x * 4 + (tid >> 6);
    int d = tid & 63;
    if (r >= N) return;
    const float* a = A + (size_t)r * 64;
    const float* f = F + (size_t)r * 64;
    float acc = 0.f;
    #pragma unroll
    for (int k = 0; k < 64; ++k) acc += a[k] * sU[d][k];
    #pragma unroll
    for (int k = 0; k < 64; ++k) acc += f[k] * sU[d][64 + k];
    out[(size_t)r * 64 + d] = tanhf(acc);
}

// ---------------------------------------------------------------------------
// K2: 32 nodes / 256-thread block; wave wv: dir = wv>>1, node half (wv&1)*16.
// Merged produce+consume per wave, no barriers in the 50-step loop.
// VALU-lean: bf16 mail from global, f32 xw in MFMA accs, bias folded into
// MFMA C-init, cvt_pk h stores, XOR-swizzled Wi LDS (2-way, was 8-way).
// ---------------------------------------------------------------------------
__global__ __launch_bounds__(256, 1) void reduce32(
    const u16*   __restrict__ srcB,      // [Nsrc][64] bf16
    const u16*   __restrict__ dstB,      // [N][64] bf16
    const int*   __restrict__ nbr_idx,   // [N][L]
    const int*   __restrict__ nbr_time,  // [N][L]
    const float* __restrict__ te,        // [L][64]
    const float* __restrict__ te_k,      // [L][64]
    const float* __restrict__ Wi,        // [2][192][64]
    const float* __restrict__ Wh,        // [2][192][64]
    const float* __restrict__ bi,        // [2][192]
    const float* __restrict__ bh,        // [2][192]
    const float* __restrict__ glin,      // [64][128]
    const float* __restrict__ agg,       // [64][128]
    float* __restrict__ out)             // [N][64]
{
    extern __shared__ __align__(16) char smem[];
    u16*   sWI    = (u16*)(smem + OFF_WI);
    u16*   sRIDp  = (u16*)(smem + OFF_RID);
    float* sEF    = (float*)(smem + OFF_EF);
    float* sEB    = (float*)(smem + OFF_EB);
    u8*    sORD   = (u8*)(smem + OFF_ORD);
    u8*    sARE   = (u8*)(smem + OFF_ARE);
    int*   sLASTN = (int*)(smem + OFF_LASTN);

    const int tid  = threadIdx.x;
    const int lane = tid & 63;
    const int wv   = tid >> 6;            // 0..3
    const int l15  = lane & 15;
    const int grp  = lane >> 4;           // 0..3
    const int lk8  = grp * 8;
    const int nb   = blockIdx.x * NODES;
    const int dir    = wv >> 1;           // 0=fwd 1=bwd
    const int base16 = (wv & 1) * 16;     // node half owned by this wave

    u16* sHw = (u16*)(smem + OFF_H) + wv * 16 * 72;   // per-wave h [16][72]

    // ---- PH0: times/ids -> stable rank, argmax(first), sorted row ids ----
    int* sTM  = (int*)(smem + OFF_WI);
    int* sNID = sTM + NODES * L;
    for (int p = tid; p < NODES * L; p += 256) {
        sTM[p]  = nbr_time[(size_t)nb * L + p];
        sNID[p] = nbr_idx[(size_t)nb * L + p];
    }
    __syncthreads();
    for (int p = tid; p < NODES * L; p += 256) {
        int m = p / L, l = p - m * L;
        int tl = sTM[p], rank = 0;
        for (int mm = 0; mm < L; ++mm) {
            int tm = sTM[m * L + mm];
            rank += (tm < tl) || (tm == tl && mm < l);
        }
        sORD[m * 52 + rank] = (u8)l;
        sARE[m * 52 + l]    = (u8)(L - 1 - rank);
    }
    if (tid < NODES) {
        int best = 0, bt = sTM[tid * L];
        for (int mm = 1; mm < L; ++mm) {
            int tm = sTM[tid * L + mm];
            if (tm > bt) { bt = tm; best = mm; }
        }
        sLASTN[tid] = sNID[tid * L + best];
    }
    __syncthreads();
    // sRID (u16) + dst staging (region H)
    u16* sDST = (u16*)(smem + OFF_H);
    for (int p = tid; p < NODES * L; p += 256) {
        int m = p / L, t = p - m * L;
        sRIDp[m * 52 + t] = (u16)sNID[m * L + sORD[m * 52 + t]];
    }
    for (int p = tid; p < NODES * 64; p += 256) {
        int m = p >> 6, d = p & 63;
        sDST[m * 72 + d] = dstB[(size_t)(nb + m) * 64 + d];
    }
    __syncthreads();

    // ---- PH2a: stage glin^T ----
    u16* sGLT = (u16*)(smem + OFF_WI);             // [128][72]
    float* sTED = (float*)(smem + OFF_WI + 18432); // [32][68]
    for (int p = tid; p < 8192; p += 256) {
        int d = p >> 7, j = p & 127;
        sGLT[j * 72 + d] = f2bf(glin[(size_t)d * 128 + j]);
    }
    __syncthreads();

    // ---- PH2b: v-GEMM (SV doubles as vv/S) + tedst GEMM ----
    float SV[4][4];
    {
        const u16* drow = sDST + (base16 + l15) * 72;
        bfx8 a0 = *(const bfx8*)(drow + lk8);
        bfx8 a1 = *(const bfx8*)(drow + 32 + lk8);
        #pragma unroll
        for (int nt = 0; nt < 4; ++nt) {
            const u16* gr = sGLT + (dir * 64 + nt * 16 + l15) * 72;
            bfx8 b0 = *(const bfx8*)(gr + lk8);
            bfx8 b1 = *(const bfx8*)(gr + 32 + lk8);
            f32x4 acc = {0.f, 0.f, 0.f, 0.f};
            acc = __builtin_amdgcn_mfma_f32_16x16x32_bf16(a0, b0, acc, 0, 0, 0);
            acc = __builtin_amdgcn_mfma_f32_16x16x32_bf16(a1, b1, acc, 0, 0, 0);
            #pragma unroll
            for (int r = 0; r < 4; ++r) SV[nt][r] = acc[r];
        }
    }
    #pragma unroll
    for (int e = 0; e < 2; ++e) {
        int it = wv * 2 + e, mt = it >> 2, nt = it & 3;
        const u16* drow = sDST + (mt * 16 + l15) * 72;
        bfx8 a0 = *(const bfx8*)(drow + lk8);
        bfx8 a1 = *(const bfx8*)(drow + 32 + lk8);
        int j = nt * 16 + l15;
        const float* tr = te + (size_t)(j < L ? j : 0) * 64;
        bfx8 b0 = pack_bf8(tr + lk8);
        bfx8 b1 = pack_bf8(tr + 32 + lk8);
        f32x4 acc = {0.f, 0.f, 0.f, 0.f};
        acc = __builtin_amdgcn_mfma_f32_16x16x32_bf16(a0, b0, acc, 0, 0, 0);
        acc = __builtin_amdgcn_mfma_f32_16x16x32_bf16(a1, b1, acc, 0, 0, 0);
        #pragma unroll
        for (int r = 0; r < 4; ++r)
            sTED[(mt * 16 + grp * 4 + r) * 68 + j] = acc[r];
    }
    __syncthreads();

    // ---- PH2c: sEF init = ted gather ----
    for (int p = tid; p < NODES * L; p += 256) {
        int m = p / L, l = p - m * L;
        sEF[m * 52 + l] = sTED[m * 68 + sARE[m * 52 + l]];
    }
    __syncthreads();

    // ---- PH2d: stage Wi blocked + XOR-swizzled [dir][kt][192][4-slot^sig][8] ----
    for (int p = tid; p < 2 * 192 * 64; p += 256) {
        int kk  = p & 63;
        int row = (p >> 6) % 192;
        int dr  = p / (192 * 64);
        int slot = ((kk & 31) >> 3) ^ ((row >> 1) & 3);
        sWI[(((dr * 2 + (kk >> 5)) * 192 + row) << 5) + slot * 8 + (kk & 7)]
            = f2bf(Wi[(size_t)(dr * 192 + row) * 64 + kk]);
    }
    // Wh fragments + folded biases in regs
    bfx8 whf[12][2];
    float cb[12];   // consume C-init: bi+bh for r,z rows; bh for n rows
    float pb[4];    // produce C-init for n rows: bi_n
    #pragma unroll
    for (int nt = 0; nt < 12; ++nt) {
        const float* wrow = Wh + (size_t)(dir * 192 + nt * 16 + l15) * 64;
        whf[nt][0] = pack_bf8(wrow + lk8);
        whf[nt][1] = pack_bf8(wrow + 32 + lk8);
        float bhv = bh[dir * 192 + nt * 16 + l15];
        cb[nt] = (nt < 8) ? (bi[dir * 192 + nt * 16 + l15] + bhv) : bhv;
    }
    #pragma unroll
    for (int c = 0; c < 4; ++c)
        pb[c] = bi[dir * 192 + 128 + c * 16 + l15];
    __syncthreads();

    f32x4 xcur[12];
    float hp[4][4];
    const int swoff = (grp ^ ((l15 >> 1) & 3)) * 8;
    const u16* wiA = sWI + (((dir * 2 + 0) * 192 + l15) << 5) + swoff;
    const u16* wiB = sWI + (((dir * 2 + 1) * 192 + l15) << 5) + swoff;

    auto produce = [&](bfx8 a0, bfx8 a1) {
        #pragma unroll
        for (int nt = 0; nt < 12; ++nt) {
            bfx8 b0 = *(const bfx8*)(wiA + nt * 512);
            bfx8 b1 = *(const bfx8*)(wiB + nt * 512);
            f32x4 z;
            if (nt >= 8) { float b = pb[nt - 8]; z = (f32x4){b, b, b, b}; }
            else         { z = (f32x4){0.f, 0.f, 0.f, 0.f}; }
            z = __builtin_amdgcn_mfma_f32_16x16x32_bf16(a0, b0, z, 0, 0, 0);
            z = __builtin_amdgcn_mfma_f32_16x16x32_bf16(a1, b1, z, 0, 0, 0);
            xcur[nt] = z;
        }
    };

    auto run_pass = [&](int pass) {
        #pragma unroll
        for (int c = 0; c < 4; ++c)
            #pragma unroll
            for (int r = 0; r < 4; ++r) {
                hp[c][r] = 0.f;
                if (pass == 1) SV[c][r] = 0.f;
                sHw[(grp * 4 + r) * 72 + c * 16 + l15] = 0;
            }
        // prologue: xw for s=0
        {
            int tt = dir ? (L - 1) : 0;
            const u16* mrow = srcB + (size_t)sRIDp[(base16 + l15) * 52 + tt] * 64;
            bfx8 a0 = *(const bfx8*)(mrow + lk8);
            bfx8 a1 = *(const bfx8*)(mrow + 32 + lk8);
            produce(a0, a1);
        }
        for (int s = 0; s < L; ++s) {
            // prefetch next-step mail (bf16, fragment-direct)
            bfx8 nA, nB;
            if (s + 1 < L) {
                int tt = dir ? (L - 2 - s) : (s + 1);
                const u16* mrow = srcB + (size_t)sRIDp[(base16 + l15) * 52 + tt] * 64;
                nA = *(const bfx8*)(mrow + lk8);
                nB = *(const bfx8*)(mrow + 32 + lk8);
            }
            bfx8 a0 = *(const bfx8*)(sHw + l15 * 72 + lk8);
            bfx8 a1 = *(const bfx8*)(sHw + l15 * 72 + 32 + lk8);
            int t = dir ? (L - 1 - s) : s;
            float al[4];
            if (pass == 1) {
                #pragma unroll
                for (int r = 0; r < 4; ++r)
                    al[r] = sEF[(base16 + grp * 4 + r) * 52 + t];   // alpha
            }
            float pe[4] = {0.f, 0.f, 0.f, 0.f};
            #pragma unroll
            for (int c = 0; c < 4; ++c) {
                f32x4 zr  = {cb[c],     cb[c],     cb[c],     cb[c]};
                f32x4 zz4 = {cb[4 + c], cb[4 + c], cb[4 + c], cb[4 + c]};
                f32x4 zn4 = {cb[8 + c], cb[8 + c], cb[8 + c], cb[8 + c]};
                zr  = __builtin_amdgcn_mfma_f32_16x16x32_bf16(a0, whf[c][0],     zr,  0, 0, 0);
                zr  = __builtin_amdgcn_mfma_f32_16x16x32_bf16(a1, whf[c][1],     zr,  0, 0, 0);
                zz4 = __builtin_amdgcn_mfma_f32_16x16x32_bf16(a0, whf[4 + c][0], zz4, 0, 0, 0);
                zz4 = __builtin_amdgcn_mfma_f32_16x16x32_bf16(a1, whf[4 + c][1], zz4, 0, 0, 0);
                zn4 = __builtin_amdgcn_mfma_f32_16x16x32_bf16(a0, whf[8 + c][0], zn4, 0, 0, 0);
                zn4 = __builtin_amdgcn_mfma_f32_16x16x32_bf16(a1, whf[8 + c][1], zn4, 0, 0, 0);
                #pragma unroll
                for (int r = 0; r < 4; ++r) {
                    float rr = fsig(xcur[c][r] + zr[r]);
                    float zz = fsig(xcur[4 + c][r] + zz4[r]);
                    float nn = ftanh(__builtin_fmaf(rr, zn4[r], xcur[8 + c][r]));
                    float h  = __builtin_fmaf(zz, hp[c][r] - nn, nn);
                    hp[c][r] = h;
                    if (pass == 0) pe[r] += h * SV[c][r];
                    else           SV[c][r] += al[r] * h;
                }
            }
            // h -> bf16 LDS via cvt_pk pairs
            #pragma unroll
            for (int r = 0; r < 4; ++r) {
                u32 p0 = cvtpk(hp[0][r], hp[1][r]);
                u32 p1 = cvtpk(hp[2][r], hp[3][r]);
                u16* hb = sHw + (grp * 4 + r) * 72 + l15;
                hb[0]  = (u16)p0;  hb[16] = (u16)(p0 >> 16);
                hb[32] = (u16)p1;  hb[48] = (u16)(p1 >> 16);
            }
            if (pass == 0) {
                #pragma unroll
                for (int r = 0; r < 4; ++r) {
                    #pragma unroll
                    for (int msk = 1; msk < 16; msk <<= 1)
                        pe[r] += __shfl_xor(pe[r], msk, 64);
                }
                if (l15 == 0) {
                    #pragma unroll
                    for (int r = 0; r < 4; ++r) {
                        int idx = (base16 + grp * 4 + r) * 52 + t;
                        if (dir == 0) sEF[idx] += pe[r];
                        else          sEB[idx]  = pe[r];
                    }
                }
            }
            if (s + 1 < L) produce(nA, nB);   // xw for s+1
        }
    };

    // ---- PH3: pass 0 (scores) ----
    run_pass(0);
    __syncthreads();

    // ---- PH4: softmax; alpha overwrites sEF ----
    if (tid < NODES) {
        int m = tid;
        float mx = -1e30f;
        for (int t = 0; t < L; ++t) {
            float v = (sEF[m * 52 + t] + sEB[m * 52 + t]) * 0.125f;
            sEF[m * 52 + t] = v;
            mx = fmaxf(mx, v);
        }
        float sum = 0.f;
        for (int t = 0; t < L; ++t) {
            float ex = __expf(sEF[m * 52 + t] - mx);
            sEF[m * 52 + t] = ex;
            sum += ex;
        }
        float rs = __builtin_amdgcn_rcpf(sum);
        for (int t = 0; t < L; ++t) sEF[m * 52 + t] *= rs;
    }
    __syncthreads();

    // ---- PH5: pass 1 (weighted hidden sum) ----
    run_pass(1);
    __syncthreads();

    // ---- PH6: epilogue ----
    u16* sHS   = (u16*)(smem + OFF_WI);          // [32][136] bf16 hsum f||b
    u16* sA9   = sHS + 32 * 136;                 // [32][136] bf16 hid || last_em
    u16* sTKT  = sA9 + 32 * 136;                 // [64][72]  bf16 te_k^T padded
    u16* sBETA = (u16*)(smem + OFF_EB);          // [32][72]  bf16

    #pragma unroll
    for (int c = 0; c < 4; ++c)
        #pragma unroll
        for (int r = 0; r < 4; ++r)
            sHS[(base16 + grp * 4 + r) * 136 + dir * 64 + c * 16 + l15] = f2bf(SV[c][r]);
    if (tid < NODES) {
        for (int t = 0; t < L; ++t)
            sBETA[tid * 72 + sARE[tid * 52 + t]] = f2bf(sEF[tid * 52 + t]);
        for (int j = L; j < 64; ++j) sBETA[tid * 72 + j] = 0;
    }
    for (int p = tid; p < 4096; p += 256) {
        int j = p >> 6, d = p & 63;
        sTKT[d * 72 + j] = (j < L) ? f2bf(te_k[(size_t)j * 64 + d]) : (u16)0;
    }
    for (int p = tid; p < NODES * 64; p += 256) {
        int m = p >> 6, d = p & 63;
        sA9[m * 136 + 64 + d] = srcB[(size_t)sLASTN[m] * 64 + d];
    }
    __syncthreads();

    // hid[m][d] = glin[d][:].hsum[m] + te_k^T[d][:].beta[m]
    #pragma unroll
    for (int e = 0; e < 2; ++e) {
        int it = wv * 2 + e, mt = it >> 2, nt = it & 3;
        bfx8 aH[4], aB[2];
        #pragma unroll
        for (int kt = 0; kt < 4; ++kt)
            aH[kt] = *(const bfx8*)(sHS + (mt * 16 + l15) * 136 + kt * 32 + lk8);
        #pragma unroll
        for (int kt = 0; kt < 2; ++kt)
            aB[kt] = *(const bfx8*)(sBETA + (mt * 16 + l15) * 72 + kt * 32 + lk8);
        f32x4 acc = {0.f, 0.f, 0.f, 0.f};
        #pragma unroll
        for (int kt = 0; kt < 4; ++kt) {
            bfx8 b = pack_bf8(glin + (size_t)(nt * 16 + l15) * 128 + kt * 32 + lk8);
            acc = __builtin_amdgcn_mfma_f32_16x16x32_bf16(aH[kt], b, acc, 0, 0, 0);
        }
        #pragma unroll
        for (int kt = 0; kt < 2; ++kt) {
            bfx8 b = *(const bfx8*)(sTKT + (nt * 16 + l15) * 72 + kt * 32 + lk8);
            acc = __builtin_amdgcn_mfma_f32_16x16x32_bf16(aB[kt], b, acc, 0, 0, 0);
        }
        #pragma unroll
        for (int r = 0; r < 4; ++r)
            sA9[(mt * 16 + grp * 4 + r) * 136 + nt * 16 + l15] = f2bf(acc[r]);
    }
    __syncthreads();

    // out[m][d] = agg[d][:64].hid[m] + agg[d][64:].last_em[m]
    #pragma unroll
    for (int e = 0; e < 2; ++e) {
        int it = wv * 2 + e, mt = it >> 2, nt = it & 3;
        bfx8 aA[4];
        #pragma unroll
        for (int kt = 0; kt < 4; ++kt)
            aA[kt] = *(const bfx8*)(sA9 + (mt * 16 + l15) * 136 + kt * 32 + lk8);
        f32x4 acc = {0.f, 0.f, 0.f, 0.f};
        #pragma unroll
        for (int kt = 0; kt < 4; ++kt) {
            bfx8 b = pack_bf8(agg + (size_t)(nt * 16 + l15) * 128 + kt * 32 + lk8);
            acc = __builtin_amdgcn_mfma_f32_16x16x32_bf16(aA[kt], b, acc, 0, 0, 0);
        }
        #pragma unroll
        for (int r = 0; r < 4; ++r)
            out[(size_t)(nb + mt * 16 + grp * 4 + r) * 64 + nt * 16 + l15] = acc[r];
    }
}

// ---------------------------------------------------------------------------
extern "C" void kernel_launch(void* const* d_in, const int* in_sizes, int n_in,
                              void* d_out, int out_size, void* d_ws, size_t ws_size,
                              hipStream_t stream)
{
    const float* user_feat     = (const float*)d_in[0];
    const float* item_feat     = (const float*)d_in[1];
    const int*   item_nbr_idx  = (const int*)d_in[2];
    const int*   item_nbr_time = (const int*)d_in[3];
    const int*   user_nbr_idx  = (const int*)d_in[4];
    const int*   user_nbr_time = (const int*)d_in[5];
    const float* W_user        = (const float*)d_in[6];
    const float* W_item        = (const float*)d_in[7];
    const float* u_te          = (const float*)d_in[8];
    const float* u_te_k        = (const float*)d_in[9];
    const float* i_te          = (const float*)d_in[10];
    const float* i_te_k        = (const float*)d_in[11];
    const float* gru_u_Wi      = (const float*)d_in[12];
    const float* gru_u_Wh      = (const float*)d_in[13];
    const float* gru_u_bi      = (const float*)d_in[14];
    const float* gru_u_bh      = (const float*)d_in[15];
    const float* gru_i_Wi      = (const float*)d_in[16];
    const float* gru_i_Wh      = (const float*)d_in[17];
    const float* gru_i_bi      = (const float*)d_in[18];
    const float* gru_i_bh      = (const float*)d_in[19];
    const float* gru_lin_u     = (const float*)d_in[20];
    const float* gru_lin_i     = (const float*)d_in[21];
    const float* agg_u         = (const float*)d_in[22];
    const float* agg_i         = (const float*)d_in[23];
    const float* upd_u         = (const float*)d_in[24];
    const float* upd_i         = (const float*)d_in[25];

    float* ws       = (float*)d_ws;
    float* user_hid = ws;
    float* item_hid = user_hid + NU * 64;
    float* item_agg = item_hid + NI * 64;
    float* user_agg = item_agg + NI * 64;
    u16*   userB    = (u16*)(user_agg + NU * 64);
    u16*   itemB    = userB + NU * 64;

    (void)hipFuncSetAttribute((const void*)reduce32,
                              hipFuncAttributeMaxDynamicSharedMemorySize, SMEM_SZ);

    hid_kernel<<<NU / 4, 256, 0, stream>>>(user_feat, W_user, user_hid, userB, NU);
    hid_kernel<<<NI / 4, 256, 0, stream>>>(item_feat, W_item, item_hid, itemB, NI);

    // 'by': user -> item, per item node
    reduce32<<<NI / NODES, 256, SMEM_SZ, stream>>>(userB, itemB,
        item_nbr_idx, item_nbr_time, i_te, i_te_k,
        gru_i_Wi, gru_i_Wh, gru_i_bi, gru_i_bh, gru_lin_i, agg_i, item_agg);

    // 'pby': item -> user, per user node
    reduce32<<<NU / NODES, 256, SMEM_SZ, stream>>>(itemB, userB,
        user_nbr_idx, user_nbr_time, u_te, u_te_k,
        gru_u_Wi, gru_u_Wh, gru_u_bi, gru_u_bh, gru_lin_u, agg_u, user_agg);

    float* out = (float*)d_out;
    upd_kernel<<<NU / 4, 256, 0, stream>>>(user_agg, user_feat, upd_u, out, NU);
    upd_kernel<<<NI / 4, 256, 0, stream>>>(item_agg, item_feat, upd_i, out + NU * 64, NI);
}